// Round 1
// baseline (128.751 us; speedup 1.0000x reference)
//
#include <hip/hip_runtime.h>
#include <math.h>

// 23-qubit statevector circuit: 23 U3 gates (qubit q acts on bit 22-q) then a
// CNOT cascade (c=bit22,t=bit21), ..., (c=bit1,t=bit0).
// The CNOT cascade is the Gray-code permutation: out[y] = mid[y ^ (y>>1)].
// Decomposition with L=14 low bits:
//   y = (m', t)  ->  x = (g9(m'), (t ^ (t>>1)) ^ ((m'&1)<<13)),  g9(v)=v^(v>>1)
// Pass 1: gates on bits 14..22 (qubits 0..8), chunk permutation on write.
// Pass 2: gates on bits 0..13 (qubits 9..22), in-chunk permutation, in-place.

#define NQ 23
#define NTOT (1u << NQ)
#define LBITS 14
#define CHUNK (1 << LBITS)   // 16384

// Compute U3 matrix for qubit q into g[8] = {u00r,u00i,u01r,u01i,u10r,u10i,u11r,u11i}
__device__ inline void u3_gate(const float* __restrict__ param, int q, float* g) {
    float a = param[3*q + 0];
    float b = param[3*q + 1];
    float c = param[3*q + 2];
    float cb = cosf(b * 0.5f), sb = sinf(b * 0.5f);
    float p = (a + c) * 0.5f, m = (a - c) * 0.5f;
    float cp = cosf(p), sp = sinf(p);
    float cm = cosf(m), sm = sinf(m);
    g[0] =  cb * cp;  g[1] = -cb * sp;   // u00 = cb*e^{-ip}
    g[2] = -sb * cm;  g[3] =  sb * sm;   // u01 = -sb*e^{-im}
    g[4] =  sb * cm;  g[5] =  sb * sm;   // u10 =  sb*e^{+im}
    g[6] =  cb * cp;  g[7] =  cb * sp;   // u11 = cb*e^{+ip}
}

// Pass 1: tile = 512 rows (bits 14..22) x 16 cols (bits 0..3); bits 4..13 = blockIdx.
__global__ __launch_bounds__(512)
void pass_high(const float* __restrict__ in_re, const float* __restrict__ in_im,
               const float* __restrict__ param,
               float* __restrict__ out_re, float* __restrict__ out_im) {
    __shared__ float lre[512][16];
    __shared__ float lim[512][16];
    __shared__ float gate[9][8];

    const int tid = threadIdx.x;
    const int blk = blockIdx.x;                 // 10 bits -> bits 4..13
    if (tid < 9) {
        // beta = tid: bit b = 14+beta, qubit q = 22-b = 8-beta
        u3_gate(param, 8 - tid, gate[tid]);
    }

    const size_t base = ((size_t)blk) << 4;
    // load 512x16 tile; float4 per lane: 2048 float4 per array, 4 iters
    for (int k = 0; k < 4; ++k) {
        int e = tid + k * 512;                  // 0..2047
        int r = e >> 2, c4 = e & 3;
        size_t gi = (((size_t)r) << 14) + base + (size_t)(c4 << 2);
        *(float4*)&lre[r][c4 << 2] = *(const float4*)&in_re[gi];
        *(float4*)&lim[r][c4 << 2] = *(const float4*)&in_im[gi];
    }
    __syncthreads();

    for (int beta = 0; beta < 9; ++beta) {
        const float u00r = gate[beta][0], u00i = gate[beta][1];
        const float u01r = gate[beta][2], u01i = gate[beta][3];
        const float u10r = gate[beta][4], u10i = gate[beta][5];
        const float u11r = gate[beta][6], u11i = gate[beta][7];
        const int lo = (1 << beta) - 1;
        for (int it = 0; it < 8; ++it) {
            int w = it * 512 + tid;             // 0..4095 = 256 pairs x 16 cols
            int col = w & 15, pr = w >> 4;      // pr 0..255
            int r0 = ((pr >> beta) << (beta + 1)) | (pr & lo);
            int r1 = r0 | (1 << beta);
            float x0r = lre[r0][col], x0i = lim[r0][col];
            float x1r = lre[r1][col], x1i = lim[r1][col];
            lre[r0][col] = u00r * x0r - u00i * x0i + u01r * x1r - u01i * x1i;
            lim[r0][col] = u00r * x0i + u00i * x0r + u01r * x1i + u01i * x1r;
            lre[r1][col] = u10r * x0r - u10i * x0i + u11r * x1r - u11i * x1i;
            lim[r1][col] = u10r * x0i + u10i * x0r + u11r * x1i + u11i * x1r;
        }
        __syncthreads();
    }

    // write back with chunk permutation: row r -> sigma(r) = Gray-decode (prefix XOR)
    for (int k = 0; k < 4; ++k) {
        int e = tid + k * 512;
        int r = e >> 2, c4 = e & 3;
        int s = r;
        s ^= s >> 1; s ^= s >> 2; s ^= s >> 4; s ^= s >> 8;
        size_t gi = (((size_t)s) << 14) + base + (size_t)(c4 << 2);
        *(float4*)&out_re[gi] = *(float4*)&lre[r][c4 << 2];
        *(float4*)&out_im[gi] = *(float4*)&lim[r][c4 << 2];
    }
}

// Pass 2: one chunk (2^14 amps) per block, gates on bits 0..13, in-place,
// final write applies in-chunk Gray gather.
__global__ __launch_bounds__(1024)
void pass_low(float* __restrict__ sre, float* __restrict__ sim,
              const float* __restrict__ param) {
    __shared__ float lre[CHUNK];
    __shared__ float lim[CHUNK];
    __shared__ float gate[14][8];

    const int tid = threadIdx.x;
    const int c = blockIdx.x;                   // chunk index (9 bits)
    if (tid < 14) {
        // bit b = tid, qubit q = 22 - b
        u3_gate(param, 22 - tid, gate[tid]);
    }

    const size_t base = ((size_t)c) << LBITS;
    for (int k = 0; k < 4; ++k) {
        int e = tid + k * 1024;                 // float4 index 0..4095
        *(float4*)&lre[e << 2] = *(const float4*)&sre[base + (size_t)(e << 2)];
        *(float4*)&lim[e << 2] = *(const float4*)&sim[base + (size_t)(e << 2)];
    }
    __syncthreads();

    for (int b = 0; b < 14; ++b) {
        const float u00r = gate[b][0], u00i = gate[b][1];
        const float u01r = gate[b][2], u01i = gate[b][3];
        const float u10r = gate[b][4], u10i = gate[b][5];
        const float u11r = gate[b][6], u11i = gate[b][7];
        const int lo = (1 << b) - 1;
        for (int it = 0; it < 8; ++it) {
            int p = it * 1024 + tid;            // 0..8191 pairs
            int i0 = ((p >> b) << (b + 1)) | (p & lo);
            int i1 = i0 | (1 << b);
            float x0r = lre[i0], x0i = lim[i0];
            float x1r = lre[i1], x1i = lim[i1];
            lre[i0] = u00r * x0r - u00i * x0i + u01r * x1r - u01i * x1i;
            lim[i0] = u00r * x0i + u00i * x0r + u01r * x1i + u01i * x1r;
            lre[i1] = u10r * x0r - u10i * x0i + u11r * x1r - u11i * x1i;
            lim[i1] = u10r * x0i + u10i * x0r + u11r * x1i + u11i * x1r;
        }
        __syncthreads();
    }

    const int cbit = (c & 1) << 13;
    for (int e = tid; e < CHUNK; e += 1024) {
        int tx = (e ^ (e >> 1)) ^ cbit;
        sre[base + e] = lre[tx];
        sim[base + e] = lim[tx];
    }
}

extern "C" void kernel_launch(void* const* d_in, const int* in_sizes, int n_in,
                              void* d_out, int out_size, void* d_ws, size_t ws_size,
                              hipStream_t stream) {
    (void)in_sizes; (void)n_in; (void)d_ws; (void)ws_size; (void)out_size;
    const float* in_re = (const float*)d_in[0];
    const float* in_im = (const float*)d_in[1];
    const float* param = (const float*)d_in[2];
    float* out_re = (float*)d_out;
    float* out_im = (float*)d_out + NTOT;

    // bits 4..13 fixed per block -> 1024 blocks
    pass_high<<<1024, 512, 0, stream>>>(in_re, in_im, param, out_re, out_im);
    // one block per 2^14-amp chunk -> 512 blocks, in-place on d_out
    pass_low<<<512, 1024, 0, stream>>>(out_re, out_im, param);
}

// Round 2
// 127.779 us; speedup vs baseline: 1.0076x; 1.0076x over previous
//
#include <hip/hip_runtime.h>
#include <math.h>

// 23-qubit statevector: 23 U3 gates (qubit q acts on global bit 22-q) then a
// CNOT cascade == Gray permutation out[y] = mid[y ^ (y>>1)].
// Split: pass_high = gates on global bits 14..22 + chunk (row) Gray-decode;
//        pass_low  = gates on global bits 0..13 + in-chunk Gray gather.
// Both passes: register-blocked sweeps (3 gates per LDS round trip), all LDS
// traffic as b128 with a 2-tap XOR swizzle; stage-in/out fused with global.

#define NQ 23
#define NTOT (1u << NQ)

// ---------- helpers ----------

__device__ __forceinline__ void u3g(const float* __restrict__ p, int q, float g[8]) {
    float a = p[3*q + 0], b = p[3*q + 1], c = p[3*q + 2];
    float cb = cosf(b * 0.5f), sb = sinf(b * 0.5f);
    float ph = (a + c) * 0.5f, m = (a - c) * 0.5f;
    float cp = cosf(ph), sp = sinf(ph);
    float cm = cosf(m),  sm = sinf(m);
    g[0] =  cb * cp;  g[1] = -cb * sp;   // u00
    g[2] = -sb * cm;  g[3] =  sb * sm;   // u01
    g[4] =  sb * cm;  g[5] =  sb * sm;   // u10
    g[6] =  cb * cp;  g[7] =  cb * sp;   // u11
}

__device__ __forceinline__ void bf(float &x0r, float &x0i, float &x1r, float &x1i,
                                   const float g[8]) {
    float y0r = g[0]*x0r - g[1]*x0i + g[2]*x1r - g[3]*x1i;
    float y0i = g[0]*x0i + g[1]*x0r + g[2]*x1i + g[3]*x1r;
    float y1r = g[4]*x0r - g[5]*x0i + g[6]*x1r - g[7]*x1i;
    float y1i = g[4]*x0i + g[5]*x0r + g[6]*x1i + g[7]*x1r;
    x0r = y0r; x0i = y0i; x1r = y1r; x1i = y1i;
}

__device__ __forceinline__ void bf4(float4 &ar, float4 &ai, float4 &br, float4 &bi,
                                    const float g[8]) {
    bf(ar.x, ai.x, br.x, bi.x, g);
    bf(ar.y, ai.y, br.y, bi.y, g);
    bf(ar.z, ai.z, br.z, bi.z, g);
    bf(ar.w, ai.w, br.w, bi.w, g);
}

// butterflies inside a float4: bit0 -> (x,y),(z,w); bit1 -> (x,z),(y,w)
__device__ __forceinline__ void bf4_c0(float4 &r, float4 &i, const float g[8]) {
    bf(r.x, i.x, r.y, i.y, g); bf(r.z, i.z, r.w, i.w, g);
}
__device__ __forceinline__ void bf4_c1(float4 &r, float4 &i, const float g[8]) {
    bf(r.x, i.x, r.z, i.z, g); bf(r.y, i.y, r.w, i.w, g);
}

// 3 gates on register-index bits 0,1,2 of x[0..7]
__device__ __forceinline__ void apply3(float4 xr[8], float4 xi[8],
                                       const float g0[8], const float g1[8], const float g2[8]) {
    bf4(xr[0],xi[0],xr[1],xi[1],g0); bf4(xr[2],xi[2],xr[3],xi[3],g0);
    bf4(xr[4],xi[4],xr[5],xi[5],g0); bf4(xr[6],xi[6],xr[7],xi[7],g0);
    bf4(xr[0],xi[0],xr[2],xi[2],g1); bf4(xr[1],xi[1],xr[3],xi[3],g1);
    bf4(xr[4],xi[4],xr[6],xi[6],g1); bf4(xr[5],xi[5],xr[7],xi[7],g1);
    bf4(xr[0],xi[0],xr[4],xi[4],g2); bf4(xr[1],xi[1],xr[5],xi[5],g2);
    bf4(xr[2],xi[2],xr[6],xi[6],g2); bf4(xr[3],xi[3],xr[7],xi[7],g2);
}

// LDS: 4096 float4 slots per plane (re/im), interleaved in 64-float blocks:
// re float4 at byte ((phys>>4)<<9)|((phys&15)<<4), im at +256.
__device__ __forceinline__ int swz(int q)  { return q ^ ((q >> 3) & 7) ^ ((q >> 6) & 7); }
__device__ __forceinline__ int la(int ph)  { return ((ph >> 4) << 9) | ((ph & 15) << 4); }

__device__ __forceinline__ int pxor14(int x) {
    x ^= x >> 1; x ^= x >> 2; x ^= x >> 4; x ^= x >> 8; return x & 0x3FFF;
}
__device__ __forceinline__ int pxor9(int x) {
    x ^= x >> 1; x ^= x >> 2; x ^= x >> 4; x ^= x >> 8; return x & 0x1FF;
}

template<int K> __device__ __forceinline__ float getc(const float4 &f) {
    if constexpr (K == 0) return f.x;
    else if constexpr (K == 1) return f.y;
    else if constexpr (K == 2) return f.z;
    else return f.w;
}

// one output float4 of the fused Gray gather (pass_low sweep 4)
template<int U>
__device__ __forceinline__ void out_u(const float4 xr[8], const float4 xi[8],
                                      int a3, int Ah, size_t cb,
                                      float4* __restrict__ or4, float4* __restrict__ oi4) {
    constexpr int p0 = 4*U, p1 = 4*U+1, p2 = 4*U+2, p3 = 4*U+3;
    constexpr int v0 = p0 ^ (p0 >> 1), v1 = p1 ^ (p1 >> 1);
    constexpr int v2 = p2 ^ (p2 >> 1), v3 = p3 ^ (p3 >> 1);
    float r0 = getc<v0 & 3>(xr[v0 >> 2]), r1 = getc<v1 & 3>(xr[v1 >> 2]);
    float r2 = getc<v2 & 3>(xr[v2 >> 2]), r3 = getc<v3 & 3>(xr[v3 >> 2]);
    float s0 = getc<v0 & 3>(xi[v0 >> 2]), s1 = getc<v1 & 3>(xi[v1 >> 2]);
    float s2 = getc<v2 & 3>(xi[v2 >> 2]), s3 = getc<v3 & 3>(xi[v3 >> 2]);
    bool b0 = (a3 & 1) != 0, b1 = (a3 & 2) != 0;
    // out[k] = g[k ^ a3]
    float t0 = b0 ? r1 : r0, t1 = b0 ? r0 : r1, t2 = b0 ? r3 : r2, t3 = b0 ? r2 : r3;
    float o0 = b1 ? t2 : t0, o1 = b1 ? t3 : t1, o2 = b1 ? t0 : t2, o3 = b1 ? t1 : t3;
    float u0 = b0 ? s1 : s0, u1 = b0 ? s0 : s1, u2 = b0 ? s3 : s2, u3 = b0 ? s2 : s3;
    float w0 = b1 ? u2 : u0, w1 = b1 ? u3 : u1, w2 = b1 ? u0 : u2, w3 = b1 ? u1 : u3;
    size_t fo = cb + (size_t)(Ah ^ U);
    or4[fo] = make_float4(o0, o1, o2, o3);
    oi4[fo] = make_float4(w0, w1, w2, w3);
}

// ---------- pass_high: gates on global bits 14..22 (qubits 8..0) ----------
// Tile: 512 rows (global bits 14..22) x 32 cols (global bits 0..4);
// block = global bits 5..13 (512 blocks). Local bits: 0..4 cols, 5..13 rows.
// 3 sweeps: S0 global->reg (gates local 5,6,7 = qubits 8,7,6) -> LDS pi1;
//           S1 LDS pi1 -> reg (gates 8,9,10 = q 5,4,3) -> LDS pi2;
//           S2 LDS pi2 -> reg (gates 11,12,13 = q 2,1,0) -> global with row
//           Gray-decode sigma(r)=pxor9(r).
__global__ __launch_bounds__(512)
void pass_high(const float* __restrict__ in_re, const float* __restrict__ in_im,
               const float* __restrict__ param,
               float* __restrict__ out_re, float* __restrict__ out_im) {
    __shared__ __align__(16) char L[131072];
    const int t = threadIdx.x;
    const int blk = blockIdx.x;
    float4 xr[8], xi[8];
    float g0[8], g1[8], g2[8];

    const float4* ir4 = (const float4*)in_re;
    const float4* ii4 = (const float4*)in_im;

    // S0: direct global loads: float4 idx = (row<<12) + (blk<<3) + (t&7),
    // row = j | ((t>>3)<<3); components = local bits {0,1}.
    {
        const int rb = (t >> 3) << 3;
        const size_t bo = ((size_t)blk << 3) + (size_t)(t & 7);
#pragma unroll
        for (int j = 0; j < 8; ++j) {
            size_t fi = (((size_t)(rb | j)) << 12) + bo;
            xr[j] = ir4[fi]; xi[j] = ii4[fi];
        }
        u3g(param, 8, g0); u3g(param, 7, g1); u3g(param, 6, g2);
        apply3(xr, xi, g0, g1, g2);
        // write pi1: base = ((t&7)<<3) | ((t>>3)&7) | ((t>>6)<<9); stride j<<6
        const int bw = ((t & 7) << 3) | ((t >> 3) & 7) | ((t >> 6) << 9);
#pragma unroll
        for (int j = 0; j < 8; ++j) {
            int a = la(swz(bw + (j << 6)));
            *(float4*)(L + a) = xr[j];
            *(float4*)(L + a + 256) = xi[j];
        }
    }
    __syncthreads();

    const int hx = (t & 7) ^ ((t >> 3) & 7);
    const int br = ((t >> 1) << 9) | ((t & 1) << 7);   // read addr base (all sweeps)

    // S1
    {
#pragma unroll
        for (int j = 0; j < 8; ++j) {
            int a = br + ((j ^ hx) << 4);
            xr[j] = *(const float4*)(L + a);
            xi[j] = *(const float4*)(L + a + 256);
        }
        u3g(param, 5, g0); u3g(param, 4, g1); u3g(param, 3, g2);
        apply3(xr, xi, g0, g1, g2);
        __syncthreads();
        // write pi2: base = ((t&63)<<3) | ((t>>6)&7); stride j<<9
        const int bw = ((t & 63) << 3) | ((t >> 6) & 7);
#pragma unroll
        for (int j = 0; j < 8; ++j) {
            int a = la(swz(bw + (j << 9)));
            *(float4*)(L + a) = xr[j];
            *(float4*)(L + a + 256) = xi[j];
        }
    }
    __syncthreads();

    // S2: read, gates q2,1,0, write to global with row Gray-decode.
    {
#pragma unroll
        for (int j = 0; j < 8; ++j) {
            int a = br + ((j ^ hx) << 4);
            xr[j] = *(const float4*)(L + a);
            xi[j] = *(const float4*)(L + a + 256);
        }
        u3g(param, 2, g0); u3g(param, 1, g1); u3g(param, 0, g2);
        apply3(xr, xi, g0, g1, g2);

        float4* or4 = (float4*)out_re;
        float4* oi4 = (float4*)out_im;
        const int rb = (t >> 3) & 63;          // row bits 0..5
        const int sb = pxor9(rb);
        const size_t bo = ((size_t)blk << 3) + (size_t)(t & 7);
        constexpr int PX9[8] = {0, 0x7F, 0xFF, 0x80, 0x1FF, 0x180, 0x100, 0x17F}; // pxor9(j<<6)
#pragma unroll
        for (int j = 0; j < 8; ++j) {
            size_t fi = (((size_t)(sb ^ PX9[j])) << 12) + bo;
            or4[fi] = xr[j]; oi4[fi] = xi[j];
        }
    }
}

// ---------- pass_low: gates on global bits 0..13 (qubits 22..9) ----------
// One 2^14-amp chunk per block (512 blocks), in place on (out_re,out_im).
// 5 sweeps: S0 global->reg (gates bits 2,3,4 = q20,19,18) -> LDS pi1;
// S1 (5,6,7=q17,16,15); S2 (8,9,10=q14,13,12); S3 (11,12,13=q11,10,9) -> id;
// S4 id->reg (gates bits 0,1 = q22,q21) -> global with in-chunk Gray gather.
__global__ __launch_bounds__(512)
void pass_low(float* __restrict__ sre, float* __restrict__ sim,
              const float* __restrict__ param) {
    __shared__ __align__(16) char L[131072];
    const int t = threadIdx.x;
    const int c = blockIdx.x;
    float4 xr[8], xi[8];
    float g0[8], g1[8], g2[8];

    float4* r4 = (float4*)sre;
    float4* i4 = (float4*)sim;
    const size_t cb = ((size_t)c) << 12;   // chunk base in float4s

    // S0: direct global loads of logical [32t, 32t+32)
    {
#pragma unroll
        for (int j = 0; j < 8; ++j) {
            size_t fi = cb + (size_t)(8 * t + j);
            xr[j] = r4[fi]; xi[j] = i4[fi];
        }
        u3g(param, 20, g0); u3g(param, 19, g1); u3g(param, 18, g2);
        apply3(xr, xi, g0, g1, g2);
        // write pi1: base = (t&7) | ((t>>3)<<6); stride j<<3
        const int bw = (t & 7) | ((t >> 3) << 6);
#pragma unroll
        for (int j = 0; j < 8; ++j) {
            int a = la(swz(bw + (j << 3)));
            *(float4*)(L + a) = xr[j];
            *(float4*)(L + a + 256) = xi[j];
        }
    }
    __syncthreads();

    const int hx = (t & 7) ^ ((t >> 3) & 7);
    const int br = ((t >> 1) << 9) | ((t & 1) << 7);

    // S1: gates q17,16,15 ; write pi2: base = ((t>>3)&7)|((t&7)<<3)|((t>>6)<<9), stride j<<6
    {
#pragma unroll
        for (int j = 0; j < 8; ++j) {
            int a = br + ((j ^ hx) << 4);
            xr[j] = *(const float4*)(L + a);
            xi[j] = *(const float4*)(L + a + 256);
        }
        u3g(param, 17, g0); u3g(param, 16, g1); u3g(param, 15, g2);
        apply3(xr, xi, g0, g1, g2);
        __syncthreads();
        const int bw = ((t >> 3) & 7) | ((t & 7) << 3) | ((t >> 6) << 9);
#pragma unroll
        for (int j = 0; j < 8; ++j) {
            int a = la(swz(bw + (j << 6)));
            *(float4*)(L + a) = xr[j];
            *(float4*)(L + a + 256) = xi[j];
        }
    }
    __syncthreads();

    // S2: gates q14,13,12 ; write pi3: base = ((t>>6)&7)|((t&63)<<3), stride j<<9
    {
#pragma unroll
        for (int j = 0; j < 8; ++j) {
            int a = br + ((j ^ hx) << 4);
            xr[j] = *(const float4*)(L + a);
            xi[j] = *(const float4*)(L + a + 256);
        }
        u3g(param, 14, g0); u3g(param, 13, g1); u3g(param, 12, g2);
        apply3(xr, xi, g0, g1, g2);
        __syncthreads();
        const int bw = ((t >> 6) & 7) | ((t & 63) << 3);
#pragma unroll
        for (int j = 0; j < 8; ++j) {
            int a = la(swz(bw + (j << 9)));
            *(float4*)(L + a) = xr[j];
            *(float4*)(L + a + 256) = xi[j];
        }
    }
    __syncthreads();

    // S3: gates q11,10,9 ; write identity layout: base = t, stride j<<9
    {
#pragma unroll
        for (int j = 0; j < 8; ++j) {
            int a = br + ((j ^ hx) << 4);
            xr[j] = *(const float4*)(L + a);
            xi[j] = *(const float4*)(L + a + 256);
        }
        u3g(param, 11, g0); u3g(param, 10, g1); u3g(param, 9, g2);
        apply3(xr, xi, g0, g1, g2);
        __syncthreads();
#pragma unroll
        for (int j = 0; j < 8; ++j) {
            int a = la(swz(t + (j << 9)));
            *(float4*)(L + a) = xr[j];
            *(float4*)(L + a + 256) = xi[j];
        }
    }
    __syncthreads();

    // S4: read identity (thread holds logical [32t,32t+32)), gates q22 (bit0),
    // q21 (bit1), then fused Gray gather to global (in place, own chunk only).
    {
#pragma unroll
        for (int j = 0; j < 8; ++j) {
            int a = br + ((j ^ hx) << 4);
            xr[j] = *(const float4*)(L + a);
            xi[j] = *(const float4*)(L + a + 256);
        }
        u3g(param, 22, g0); u3g(param, 21, g1);
#pragma unroll
        for (int j = 0; j < 8; ++j) { bf4_c0(xr[j], xi[j], g0); bf4_c1(xr[j], xi[j], g1); }

        const int A  = pxor14(t << 5) ^ ((c & 1) ? 0x3FFF : 0);
        const int a3 = A & 3;
        const int Ah = A >> 2;
        out_u<0>(xr, xi, a3, Ah, cb, r4, i4);
        out_u<1>(xr, xi, a3, Ah, cb, r4, i4);
        out_u<2>(xr, xi, a3, Ah, cb, r4, i4);
        out_u<3>(xr, xi, a3, Ah, cb, r4, i4);
        out_u<4>(xr, xi, a3, Ah, cb, r4, i4);
        out_u<5>(xr, xi, a3, Ah, cb, r4, i4);
        out_u<6>(xr, xi, a3, Ah, cb, r4, i4);
        out_u<7>(xr, xi, a3, Ah, cb, r4, i4);
    }
}

extern "C" void kernel_launch(void* const* d_in, const int* in_sizes, int n_in,
                              void* d_out, int out_size, void* d_ws, size_t ws_size,
                              hipStream_t stream) {
    (void)in_sizes; (void)n_in; (void)d_ws; (void)ws_size; (void)out_size;
    const float* in_re = (const float*)d_in[0];
    const float* in_im = (const float*)d_in[1];
    const float* param = (const float*)d_in[2];
    float* out_re = (float*)d_out;
    float* out_im = (float*)d_out + NTOT;

    pass_high<<<512, 512, 0, stream>>>(in_re, in_im, param, out_re, out_im);
    pass_low <<<512, 512, 0, stream>>>(out_re, out_im, param);
}

// Round 4
// 88.274 us; speedup vs baseline: 1.4585x; 1.4475x over previous
//
#include <hip/hip_runtime.h>
#include <math.h>

// 23-qubit statevector: 23 U3 gates (qubit q acts on global bit 22-q) then a
// CNOT cascade == Gray permutation out[y] = mid[y ^ (y>>1)].
// pass_high: gates on global bits {0,1} u {14..22} + chunk (row) Gray-decode
//            sigma = pxor9 folded into its writes.
// pass_low : gates on global bits {2..13} + in-chunk Gray gather:
//            out addr t = pxor14(x) ^ 0x3FFF*(c&1)   (amp-level, verified R2)
//            => t_f4 = pxor12(x_f4) ^ 0xFFF*(c&1); comps reversed iff
//               b = parity(x_f4) ^ (c&1).
// Structure per kernel: 1024 threads, 16 amps/thread (4 float4 re + 4 im).
//   - 2 gate bits on float4 components (pass_high only)
//   - 2 gate bits on register index
//   - 6 gate bits on lane bits via __shfl_xor butterflies (no barrier)
//   - 4 gate bits cross-wave via ONE swizzled-LDS round trip (one barrier)
// Gate coeffs: lane l computes qubit l's U3 once; broadcast via __shfl.

#define NTOT (1u << 23)

struct G8 { float r00,i00,r01,i01,r10,i10,r11,i11; };

__device__ __forceinline__ G8 u3_lane(const float* __restrict__ p, int q) {
    float a = p[3*q+0], b = p[3*q+1], c = p[3*q+2];
    float cb = cosf(b*0.5f), sb = sinf(b*0.5f);
    float ph = (a+c)*0.5f, m = (a-c)*0.5f;
    float cp = cosf(ph), sp = sinf(ph);
    float cm = cosf(m),  sm = sinf(m);
    G8 g;
    g.r00 =  cb*cp; g.i00 = -cb*sp;
    g.r01 = -sb*cm; g.i01 =  sb*sm;
    g.r10 =  sb*cm; g.i10 =  sb*sm;
    g.r11 =  cb*cp; g.i11 =  cb*sp;
    return g;
}

__device__ __forceinline__ G8 bc(const G8& m, int q) {
    G8 g;
    g.r00 = __shfl(m.r00, q); g.i00 = __shfl(m.i00, q);
    g.r01 = __shfl(m.r01, q); g.i01 = __shfl(m.i01, q);
    g.r10 = __shfl(m.r10, q); g.i10 = __shfl(m.i10, q);
    g.r11 = __shfl(m.r11, q); g.i11 = __shfl(m.i11, q);
    return g;
}

__device__ __forceinline__ void bfs(float& x0r, float& x0i, float& x1r, float& x1i, const G8& g) {
    float y0r = g.r00*x0r - g.i00*x0i + g.r01*x1r - g.i01*x1i;
    float y0i = g.r00*x0i + g.i00*x0r + g.r01*x1i + g.i01*x1r;
    float y1r = g.r10*x0r - g.i10*x0i + g.r11*x1r - g.i11*x1i;
    float y1i = g.r10*x0i + g.i10*x0r + g.r11*x1i + g.i11*x1r;
    x0r=y0r; x0i=y0i; x1r=y1r; x1i=y1i;
}

__device__ __forceinline__ void bf4v(float4& ar, float4& ai, float4& br, float4& bi, const G8& g) {
    bfs(ar.x, ai.x, br.x, bi.x, g);
    bfs(ar.y, ai.y, br.y, bi.y, g);
    bfs(ar.z, ai.z, br.z, bi.z, g);
    bfs(ar.w, ai.w, br.w, bi.w, g);
}

// component-bit gates: bit0 -> (x,y),(z,w); bit1 -> (x,z),(y,w)
__device__ __forceinline__ void bfc0(float4& r, float4& i, const G8& g) {
    bfs(r.x, i.x, r.y, i.y, g); bfs(r.z, i.z, r.w, i.w, g);
}
__device__ __forceinline__ void bfc1(float4& r, float4& i, const G8& g) {
    bfs(r.x, i.x, r.z, i.z, g); bfs(r.y, i.y, r.w, i.w, g);
}

// register-index-bit gates
__device__ __forceinline__ void reg_gate0(float4 (&xr)[4], float4 (&xi)[4], const G8& g) {
    bf4v(xr[0],xi[0],xr[1],xi[1],g); bf4v(xr[2],xi[2],xr[3],xi[3],g);
}
__device__ __forceinline__ void reg_gate1(float4 (&xr)[4], float4 (&xi)[4], const G8& g) {
    bf4v(xr[0],xi[0],xr[2],xi[2],g); bf4v(xr[1],xi[1],xr[3],xi[3],g);
}

__device__ __forceinline__ float4 sx4(float4 v, int m) {
    float4 r;
    r.x = __shfl_xor(v.x, m); r.y = __shfl_xor(v.y, m);
    r.z = __shfl_xor(v.z, m); r.w = __shfl_xor(v.w, m);
    return r;
}

// lane-bit gate: partner = lane ^ m; own half selected by 'bit'
__device__ __forceinline__ void lane_gate(float4 (&xr)[4], float4 (&xi)[4], const G8& g, int bit, int m) {
    float cor = bit ? g.r11 : g.r00, coi = bit ? g.i11 : g.i00;
    float cpr = bit ? g.r10 : g.r01, cpi = bit ? g.i10 : g.i01;
#pragma unroll
    for (int i = 0; i < 4; ++i) {
        float4 pr = sx4(xr[i], m), pi = sx4(xi[i], m);
        float4 nr, ni;
        nr.x = cor*xr[i].x - coi*xi[i].x + cpr*pr.x - cpi*pi.x;
        ni.x = cor*xi[i].x + coi*xr[i].x + cpr*pi.x + cpi*pr.x;
        nr.y = cor*xr[i].y - coi*xi[i].y + cpr*pr.y - cpi*pi.y;
        ni.y = cor*xi[i].y + coi*xr[i].y + cpr*pi.y + cpi*pr.y;
        nr.z = cor*xr[i].z - coi*xi[i].z + cpr*pr.z - cpi*pi.z;
        ni.z = cor*xi[i].z + coi*xr[i].z + cpr*pi.z + cpi*pr.z;
        nr.w = cor*xr[i].w - coi*xi[i].w + cpr*pr.w - cpi*pi.w;
        ni.w = cor*xi[i].w + coi*xr[i].w + cpr*pi.w + cpi*pr.w;
        xr[i] = nr; xi[i] = ni;
    }
}

// LDS: slot q (12 bits) -> byte la(swz(q)) for re, +256 for im
__device__ __forceinline__ int swz(int q) { return q ^ ((q>>3)&7) ^ ((q>>6)&7); }
__device__ __forceinline__ int la(int p)  { return ((p>>4)<<9) | ((p&15)<<4); }

__device__ __forceinline__ int pxor12(int x) { x^=x>>1; x^=x>>2; x^=x>>4; x^=x>>8; return x & 0xFFF; }
__device__ __forceinline__ int pxor9(int x)  { x^=x>>1; x^=x>>2; x^=x>>4; x^=x>>8; return x & 0x1FF; }

// ---------------- pass_high ----------------
// local bits: {0,1}=comps(global 0,1), {2,3,4}=colf4(global 2,3,4),
// {5..13}=rows(global 14..22). Gates: q22,q21 (comps) + q8..q0 (rows).
// blk = global bits 5..13 (9 bits, 512 blocks).
__global__ __launch_bounds__(1024)
void pass_high(const float* __restrict__ in_re, const float* __restrict__ in_im,
               const float* __restrict__ param,
               float* __restrict__ out_re, float* __restrict__ out_im) {
    __shared__ __align__(16) char L[131072];
    const int tid = threadIdx.x, blk = blockIdx.x;
    const int l = tid & 63, w = tid >> 6;
    G8 my = u3_lane(param, l < 23 ? l : 22);
    float4 xr[4], xi[4];

    const float4* R4 = (const float4*)in_re;
    const float4* I4 = (const float4*)in_im;
    // load: row = j | ((l>>3)<<2) | (w<<5); colf4 = l&7  (128B contiguous per 8 lanes)
    const int rbase = ((l>>3)<<2) | (w<<5);
    const size_t gb0 = ((size_t)blk << 3) | (size_t)(l & 7);
#pragma unroll
    for (int j = 0; j < 4; ++j) {
        size_t gi = (((size_t)(rbase | j)) << 12) | gb0;
        xr[j] = R4[gi]; xi[j] = I4[gi];
    }
    // comps gates: bit0 -> q22, bit1 -> q21
    { G8 g = bc(my,22);
#pragma unroll
      for (int j = 0; j < 4; ++j) bfc0(xr[j], xi[j], g); }
    { G8 g = bc(my,21);
#pragma unroll
      for (int j = 0; j < 4; ++j) bfc1(xr[j], xi[j], g); }
    // reg gates: j bit0 = local5 = q8; j bit1 = local6 = q7
    { G8 g = bc(my,8); reg_gate0(xr, xi, g); }
    { G8 g = bc(my,7); reg_gate1(xr, xi, g); }
    // lane gates: mask8 = local7 = q6; mask16 = q5; mask32 = q4
    { G8 g = bc(my,6); lane_gate(xr, xi, g, (l>>3)&1,  8); }
    { G8 g = bc(my,5); lane_gate(xr, xi, g, (l>>4)&1, 16); }
    { G8 g = bc(my,4); lane_gate(xr, xi, g, (l>>5)&1, 32); }
    // RT write: identity q-space local{2..13}: q = (l&7)|(j<<3)|((l>>3)<<5)|(w<<8)
#pragma unroll
    for (int j = 0; j < 4; ++j) {
        int a = la(swz((l & 7) | (j << 3) | ((l >> 3) << 5) | (w << 8)));
        *(float4*)(L + a) = xr[j];
        *(float4*)(L + a + 256) = xi[j];
    }
    __syncthreads();
    // RT read: q_r = l{2..5} | w<<4 | j'<<8 | (l&3)<<10
    const int qb = ((l >> 2) & 15) | (w << 4) | ((l & 3) << 10);
#pragma unroll
    for (int j = 0; j < 4; ++j) {
        int a = la(swz(qb | (j << 8)));
        xr[j] = *(const float4*)(L + a);
        xi[j] = *(const float4*)(L + a + 256);
    }
    // post gates: j' bit0 = local10 = q3; bit1 = q2; mask1 = local12 = q1; mask2 = q0
    { G8 g = bc(my,3); reg_gate0(xr, xi, g); }
    { G8 g = bc(my,2); reg_gate1(xr, xi, g); }
    { G8 g = bc(my,1); lane_gate(xr, xi, g, (l>>0)&1, 1); }
    { G8 g = bc(my,0); lane_gate(xr, xi, g, (l>>1)&1, 2); }
    // store with row Gray-decode sigma = pxor9(row):
    // row = l'5 | (w<<1) | (j'<<5) | ((l&3)<<7); colf4 = (l>>2)&7
    float4* OR4 = (float4*)out_re;
    float4* OI4 = (float4*)out_im;
    const int row_base = ((l >> 5) & 1) | (w << 1) | ((l & 3) << 7);
    const int sb = pxor9(row_base);
    const size_t ob0 = ((size_t)blk << 3) | (size_t)((l >> 2) & 7);
    constexpr int SM[4] = {0, 0x3F, 0x7F, 0x40};   // pxor9(j'<<5)
#pragma unroll
    for (int j = 0; j < 4; ++j) {
        size_t oi = (((size_t)(sb ^ SM[j])) << 12) | ob0;
        OR4[oi] = xr[j]; OI4[oi] = xi[j];
    }
}

// ---------------- pass_low ----------------
// chunk c = global bits 14..22 (512 blocks). local bits 0..13; gates {2..13}.
// pre : l = local{2..7} (masks 1..32 -> q20..q15), j = local{8,9} (q14,q13)
// post: j' = local{10,11} (q12,q11), masks 1,2 = local{12,13} (q10,q9)
// final: Gray gather out addr t = pxor14(x) ^ 0x3FFF*(c&1), in place:
//   t_f4 = pxor12(x_f4) ^ 0xFFF*c0; comps (x,y,w,z) reversed iff parity(x_f4)^c0.
__global__ __launch_bounds__(1024)
void pass_low(float* __restrict__ sre, float* __restrict__ sim,
              const float* __restrict__ param) {
    __shared__ __align__(16) char L[131072];
    const int tid = threadIdx.x, c = blockIdx.x;
    const int l = tid & 63, w = tid >> 6;
    G8 my = u3_lane(param, l < 23 ? l : 22);
    float4 xr[4], xi[4];

    float4* R4 = (float4*)sre;
    float4* I4 = (float4*)sim;
    const size_t gb = ((size_t)c << 12) | (size_t)(l | (w << 8));
#pragma unroll
    for (int j = 0; j < 4; ++j) {
        xr[j] = R4[gb + (size_t)(j << 6)];
        xi[j] = I4[gb + (size_t)(j << 6)];
    }
    // lane gates local{2..7} = q20..q15
    { G8 g = bc(my,20); lane_gate(xr, xi, g, (l>>0)&1,  1); }
    { G8 g = bc(my,19); lane_gate(xr, xi, g, (l>>1)&1,  2); }
    { G8 g = bc(my,18); lane_gate(xr, xi, g, (l>>2)&1,  4); }
    { G8 g = bc(my,17); lane_gate(xr, xi, g, (l>>3)&1,  8); }
    { G8 g = bc(my,16); lane_gate(xr, xi, g, (l>>4)&1, 16); }
    { G8 g = bc(my,15); lane_gate(xr, xi, g, (l>>5)&1, 32); }
    // reg gates: local{8,9} = q14,q13
    { G8 g = bc(my,14); reg_gate0(xr, xi, g); }
    { G8 g = bc(my,13); reg_gate1(xr, xi, g); }
    // RT write: identity q = l | (j<<6) | (w<<8)
#pragma unroll
    for (int j = 0; j < 4; ++j) {
        int a = la(swz(l | (j << 6) | (w << 8)));
        *(float4*)(L + a) = xr[j];
        *(float4*)(L + a + 256) = xi[j];
    }
    __syncthreads();
    const int qb = ((l >> 2) & 15) | (w << 4) | ((l & 3) << 10);
#pragma unroll
    for (int j = 0; j < 4; ++j) {
        int a = la(swz(qb | (j << 8)));
        xr[j] = *(const float4*)(L + a);
        xi[j] = *(const float4*)(L + a + 256);
    }
    // post gates: j' = local{10,11} = q12,q11; masks 1,2 = local{12,13} = q10,q9
    { G8 g = bc(my,12); reg_gate0(xr, xi, g); }
    { G8 g = bc(my,11); reg_gate1(xr, xi, g); }
    { G8 g = bc(my,10); lane_gate(xr, xi, g, (l>>0)&1, 1); }
    { G8 g = bc(my, 9); lane_gate(xr, xi, g, (l>>1)&1, 2); }
    // Gray gather store: x_f4 = qb | (j'<<8); t_f4 = pxor12(x_f4) ^ 0xFFF*c0.
    // comps s = (x, y, w, z); out = reversed(s) iff b = parity(x_f4) ^ c0.
    const int px0 = pxor12(qb);
    const int codd = c & 1;
    const int A12 = codd ? 0xFFF : 0;
    constexpr int PM[4] = {0, 0x1FF, 0x3FF, 0x200};  // pxor12(j'<<8)
#pragma unroll
    for (int j = 0; j < 4; ++j) {
        int pxj = px0 ^ PM[j];
        int of4 = pxj ^ A12;
        int b = (pxj ^ codd) & 1;
        float s0r = xr[j].x, s1r = xr[j].y, s2r = xr[j].w, s3r = xr[j].z;
        float s0i = xi[j].x, s1i = xi[j].y, s2i = xi[j].w, s3i = xi[j].z;
        float o0r = b ? s3r : s0r, o1r = b ? s2r : s1r, o2r = b ? s1r : s2r, o3r = b ? s0r : s3r;
        float o0i = b ? s3i : s0i, o1i = b ? s2i : s1i, o2i = b ? s1i : s2i, o3i = b ? s0i : s3i;
        size_t oo = ((size_t)c << 12) | (size_t)of4;
        R4[oo] = make_float4(o0r, o1r, o2r, o3r);
        I4[oo] = make_float4(o0i, o1i, o2i, o3i);
    }
}

extern "C" void kernel_launch(void* const* d_in, const int* in_sizes, int n_in,
                              void* d_out, int out_size, void* d_ws, size_t ws_size,
                              hipStream_t stream) {
    (void)in_sizes; (void)n_in; (void)d_ws; (void)ws_size; (void)out_size;
    const float* in_re = (const float*)d_in[0];
    const float* in_im = (const float*)d_in[1];
    const float* param = (const float*)d_in[2];
    float* out_re = (float*)d_out;
    float* out_im = (float*)d_out + NTOT;

    pass_high<<<512, 1024, 0, stream>>>(in_re, in_im, param, out_re, out_im);
    pass_low <<<512, 1024, 0, stream>>>(out_re, out_im, param);
}

// Round 5
// 77.136 us; speedup vs baseline: 1.6691x; 1.1444x over previous
//
#include <hip/hip_runtime.h>
#include <math.h>

// 23-qubit statevector: 23 U3 gates (qubit q acts on global bit 22-q), then a
// CNOT cascade == Gray permutation out[y] = mid[y ^ (y>>1)].
// pass_high: gates on global bits {0,1}u{14..22}, chunk-level Gray-decode
//            sigma = pxor9(row) folded into stores (verified R4).
// pass_low : gates on global bits {2..13}, in-chunk Gray gather
//            t = pxor14(x) ^ 0x3FFF*(c&1) folded into stores (verified R4).
// Per kernel: 1024 thr/block, 512 blocks, 16 amps/thread (4 f4 re + 4 f4 im).
// Two gate epochs around ONE LDS round trip. Cheap gate slots per epoch:
//   comp bits (in-f4), reg bits (in-thread), lane xor1/xor2 (DPP quad_perm),
//   lane xor16 (ds_swizzle/permlane16_swap), lane xor32 (permlane32_swap).
// Gate coeffs: lane q computes qubit q's U3; broadcast via v_readlane (SGPR).

#define NTOT (1u << 23)

typedef unsigned int u2 __attribute__((ext_vector_type(2)));

struct G8 { float r00,i00,r01,i01,r10,i10,r11,i11; };

__device__ __forceinline__ G8 u3_lane(const float* __restrict__ p, int q) {
    float a = p[3*q+0], b = p[3*q+1], c = p[3*q+2];
    float cb = cosf(b*0.5f), sb = sinf(b*0.5f);
    float ph = (a+c)*0.5f, m = (a-c)*0.5f;
    float cp = cosf(ph), sp = sinf(ph);
    float cm = cosf(m),  sm = sinf(m);
    G8 g;
    g.r00 =  cb*cp; g.i00 = -cb*sp;
    g.r01 = -sb*cm; g.i01 =  sb*sm;
    g.r10 =  sb*cm; g.i10 =  sb*sm;
    g.r11 =  cb*cp; g.i11 =  cb*sp;
    return g;
}

__device__ __forceinline__ float rdl(float v, int q) {
    return __uint_as_float(__builtin_amdgcn_readlane(__float_as_uint(v), q));
}
// broadcast lane q's gate matrix into (mostly) SGPRs
__device__ __forceinline__ G8 gread(const G8& m, int q) {
    G8 g;
    g.r00=rdl(m.r00,q); g.i00=rdl(m.i00,q);
    g.r01=rdl(m.r01,q); g.i01=rdl(m.i01,q);
    g.r10=rdl(m.r10,q); g.i10=rdl(m.i10,q);
    g.r11=rdl(m.r11,q); g.i11=rdl(m.i11,q);
    return g;
}

__device__ __forceinline__ void bfs(float& x0r, float& x0i, float& x1r, float& x1i, const G8& g) {
    float y0r = g.r00*x0r - g.i00*x0i + g.r01*x1r - g.i01*x1i;
    float y0i = g.r00*x0i + g.i00*x0r + g.r01*x1i + g.i01*x1r;
    float y1r = g.r10*x0r - g.i10*x0i + g.r11*x1r - g.i11*x1i;
    float y1i = g.r10*x0i + g.i10*x0r + g.r11*x1i + g.i11*x1r;
    x0r=y0r; x0i=y0i; x1r=y1r; x1i=y1i;
}
__device__ __forceinline__ void bf4v(float4& ar, float4& ai, float4& br, float4& bi, const G8& g) {
    bfs(ar.x, ai.x, br.x, bi.x, g);
    bfs(ar.y, ai.y, br.y, bi.y, g);
    bfs(ar.z, ai.z, br.z, bi.z, g);
    bfs(ar.w, ai.w, br.w, bi.w, g);
}
// comp-bit gates: bit0 -> (x,y),(z,w); bit1 -> (x,z),(y,w)
__device__ __forceinline__ void bfc0(float4& r, float4& i, const G8& g) {
    bfs(r.x, i.x, r.y, i.y, g); bfs(r.z, i.z, r.w, i.w, g);
}
__device__ __forceinline__ void bfc1(float4& r, float4& i, const G8& g) {
    bfs(r.x, i.x, r.z, i.z, g); bfs(r.y, i.y, r.w, i.w, g);
}
__device__ __forceinline__ void reg_gate0(float4 (&xr)[4], float4 (&xi)[4], const G8& g) {
    bf4v(xr[0],xi[0],xr[1],xi[1],g); bf4v(xr[2],xi[2],xr[3],xi[3],g);
}
__device__ __forceinline__ void reg_gate1(float4 (&xr)[4], float4 (&xi)[4], const G8& g) {
    bf4v(xr[0],xi[0],xr[2],xi[2],g); bf4v(xr[1],xi[1],xr[3],xi[3],g);
}

// ---- lane-partner fetchers ----
// xor1 / xor2 via DPP quad_perm (pure VALU)
__device__ __forceinline__ float p_dpp1(float x) {
    return __uint_as_float((unsigned)__builtin_amdgcn_update_dpp(
        0, (int)__float_as_uint(x), 0xB1, 0xF, 0xF, true));   // quad_perm [1,0,3,2]
}
__device__ __forceinline__ float p_dpp2(float x) {
    return __uint_as_float((unsigned)__builtin_amdgcn_update_dpp(
        0, (int)__float_as_uint(x), 0x4E, 0xF, 0xF, true));   // quad_perm [2,3,0,1]
}
// xor16: permlane16_swap if available, else ds_swizzle (32-lane groups, xor16 ok)
__device__ __forceinline__ float p_x16(float x, int hi) {
#if __has_builtin(__builtin_amdgcn_permlane16_swap)
    u2 r = __builtin_amdgcn_permlane16_swap(__float_as_uint(x), __float_as_uint(x), false, false);
    return __uint_as_float(hi ? r[0] : r[1]);
#else
    (void)hi;
    return __uint_as_float((unsigned)__builtin_amdgcn_ds_swizzle(
        (int)__float_as_uint(x), 0x401F));                    // BitMode xor 16
#endif
}
// xor32: permlane32_swap if available, else shfl
__device__ __forceinline__ float p_x32(float x, int hi) {
#if __has_builtin(__builtin_amdgcn_permlane32_swap)
    u2 r = __builtin_amdgcn_permlane32_swap(__float_as_uint(x), __float_as_uint(x), false, false);
    return __uint_as_float(hi ? r[0] : r[1]);
#else
    (void)hi;
    return __shfl_xor(x, 32, 64);
#endif
}

__device__ __forceinline__ void pcomb(float4 (&xr)[4], float4 (&xi)[4],
                                      const float4 (&pr)[4], const float4 (&pi)[4],
                                      const G8& g, int bit) {
    float cor = bit ? g.r11 : g.r00, coi = bit ? g.i11 : g.i00;
    float cpr = bit ? g.r10 : g.r01, cpi = bit ? g.i10 : g.i01;
#pragma unroll
    for (int i = 0; i < 4; ++i) {
        float4 nr, ni;
        nr.x = cor*xr[i].x - coi*xi[i].x + cpr*pr[i].x - cpi*pi[i].x;
        ni.x = cor*xi[i].x + coi*xr[i].x + cpr*pi[i].x + cpi*pr[i].x;
        nr.y = cor*xr[i].y - coi*xi[i].y + cpr*pr[i].y - cpi*pi[i].y;
        ni.y = cor*xi[i].y + coi*xr[i].y + cpr*pi[i].y + cpi*pr[i].y;
        nr.z = cor*xr[i].z - coi*xi[i].z + cpr*pr[i].z - cpi*pi[i].z;
        ni.z = cor*xi[i].z + coi*xr[i].z + cpr*pi[i].z + cpi*pr[i].z;
        nr.w = cor*xr[i].w - coi*xi[i].w + cpr*pr[i].w - cpi*pi[i].w;
        ni.w = cor*xi[i].w + coi*xr[i].w + cpr*pi[i].w + cpi*pr[i].w;
        xr[i] = nr; xi[i] = ni;
    }
}

#define MAKE_PGATE(NAME, FETCH)                                                     \
__device__ __forceinline__ void NAME(float4 (&xr)[4], float4 (&xi)[4],              \
                                     const G8& g, int bit, int hi) {                \
    float4 pr[4], pi[4];                                                            \
    _Pragma("unroll")                                                               \
    for (int i = 0; i < 4; ++i) {                                                   \
        pr[i].x = FETCH(xr[i].x); pr[i].y = FETCH(xr[i].y);                         \
        pr[i].z = FETCH(xr[i].z); pr[i].w = FETCH(xr[i].w);                         \
        pi[i].x = FETCH(xi[i].x); pi[i].y = FETCH(xi[i].y);                         \
        pi[i].z = FETCH(xi[i].z); pi[i].w = FETCH(xi[i].w);                         \
    }                                                                               \
    (void)hi; pcomb(xr, xi, pr, pi, g, bit);                                        \
}
#define F_DPP1(v) p_dpp1(v)
#define F_DPP2(v) p_dpp2(v)
#define F_X16(v)  p_x16(v, hi)
#define F_X32(v)  p_x32(v, hi)
MAKE_PGATE(gate_dpp1, F_DPP1)
MAKE_PGATE(gate_dpp2, F_DPP2)
MAKE_PGATE(gate_x16,  F_X16)
MAKE_PGATE(gate_x32,  F_X32)

__device__ __forceinline__ int pxor12(int x) { x^=x>>1; x^=x>>2; x^=x>>4; x^=x>>8; return x & 0xFFF; }
__device__ __forceinline__ int pxor9(int x)  { x^=x>>1; x^=x>>2; x^=x>>4; x^=x>>8; return x & 0x1FF; }

// ---------------- pass_high ----------------
// L1: F = row<<12 | blk<<3 | colf4; colf4 = l&7 (g2,g3,g4: no gates);
//     row = (l>>3) | (j<<3) | (w<<5)  (g14..g22); comps = g0,g1 (q22,q21).
// Epoch A: bfc0=q22, bfc1=q21, reg0=q5(g17), reg1=q4(g18), x16=q7(g15), x32=q6(g16).
// RT: write slot (w<<8)|(j<<6)|l (linear); read L2 with
//     l'0=g22, l'1=g2, l'2=g3, l'3=g4, l'4=g20, l'5=g21, j'=(g14,g19), w'=(g15..g18).
// Epoch B: reg0=q8(g14), reg1=q3(g19), dpp1=q0(g22), x16=q2(g20), x32=q1(g21).
// Store: F = pxor9(row)<<12 | blk<<3 | colf4  (row Gray-decode, verified R4).
__global__ __launch_bounds__(1024)
void pass_high(const float* __restrict__ in_re, const float* __restrict__ in_im,
               const float* __restrict__ param,
               float* __restrict__ out_re, float* __restrict__ out_im) {
    __shared__ __align__(16) char L[131072];
    const int tid = threadIdx.x, blk = blockIdx.x;
    const int l = tid & 63, w = tid >> 6;
    G8 my = u3_lane(param, l < 23 ? l : 22);
    float4 xr[4], xi[4];

    const float4* R4p = (const float4*)in_re;
    const float4* I4p = (const float4*)in_im;
    const int rb = (l >> 3) | (w << 5);
    const size_t gb0 = ((size_t)blk << 3) | (size_t)(l & 7);
#pragma unroll
    for (int j = 0; j < 4; ++j) {
        size_t gi = (((size_t)(rb | (j << 3))) << 12) | gb0;
        xr[j] = R4p[gi]; xi[j] = I4p[gi];
    }
    const int b1  = l & 1;
    const int h16 = (l >> 4) & 1, h32 = (l >> 5) & 1;

    // Epoch A
    { G8 g = gread(my,22);
#pragma unroll
      for (int j = 0; j < 4; ++j) bfc0(xr[j], xi[j], g); }
    { G8 g = gread(my,21);
#pragma unroll
      for (int j = 0; j < 4; ++j) bfc1(xr[j], xi[j], g); }
    { G8 g = gread(my,5); reg_gate0(xr, xi, g); }
    { G8 g = gread(my,4); reg_gate1(xr, xi, g); }
    { G8 g = gread(my,7); gate_x16(xr, xi, g, h16, h16); }
    { G8 g = gread(my,6); gate_x32(xr, xi, g, h32, h32); }

    // RT write (linear slots)
#pragma unroll
    for (int j = 0; j < 4; ++j) {
        int a = ((w << 8) | (j << 6) | l) << 4;
        *(float4*)(L + a) = xr[j];
        *(float4*)(L + a + 65536) = xi[j];
    }
    __syncthreads();
    // RT read: s = colf4 | (row&7)<<3 | ((row>>3)&3)<<6 | (row>>5)<<8
    const int sbase = ((l >> 1) & 7) | ((w & 3) << 4) | (((w >> 2) & 3) << 6)
                    | (((l >> 4) & 3) << 9) | ((l & 1) << 11);
    constexpr int OFF[4] = {0, 8, 256, 264};   // j'0<<3 | j'1<<8
#pragma unroll
    for (int j = 0; j < 4; ++j) {
        int a = (sbase | OFF[j]) << 4;
        xr[j] = *(const float4*)(L + a);
        xi[j] = *(const float4*)(L + a + 65536);
    }

    // Epoch B
    { G8 g = gread(my,8); reg_gate0(xr, xi, g); }
    { G8 g = gread(my,3); reg_gate1(xr, xi, g); }
    { G8 g = gread(my,0); gate_dpp1(xr, xi, g, b1, 0); }
    { G8 g = gread(my,2); gate_x16(xr, xi, g, h16, h16); }
    { G8 g = gread(my,1); gate_x32(xr, xi, g, h32, h32); }

    // Store with sigma = pxor9(row)
    float4* OR4 = (float4*)out_re;
    float4* OI4 = (float4*)out_im;
    const int row_base = ((w & 15) << 1) | (((l >> 4) & 3) << 6) | ((l & 1) << 8);
    const int sg = pxor9(row_base);
    const size_t ob = ((size_t)blk << 3) | (size_t)((l >> 1) & 7);
    constexpr int SJ[4] = {0, 0x01, 0x3F, 0x3E};   // pxor9(j'0<<0 ^ j'1<<5)
#pragma unroll
    for (int j = 0; j < 4; ++j) {
        size_t F = (((size_t)(sg ^ SJ[j])) << 12) | ob;
        OR4[F] = xr[j]; OI4[F] = xi[j];
    }
}

// ---------------- pass_low ----------------
// chunk c = global bits 14..22. L1: f4 slot s = l | (j<<6) | (w<<8) = (g2..g13).
// Epoch A: dpp1=q20(g2), dpp2=q19(g3), x16=q16(g6), x32=q15(g7), reg0=q14(g8), reg1=q13(g9).
// RT read L2: l'0=g4, l'1=g5, l'2=g2, l'3=g3, l'4=g12, l'5=g13, j'=(g10,g11), w'=(g6..g9).
// Epoch B: dpp1=q18(g4), dpp2=q17(g5), reg0=q12(g10), reg1=q11(g11), x16=q10(g12), x32=q9(g13).
// Store: t_f4 = pxor12(v) ^ 0xFFF*c0, comps (x,y,w,z) reversed iff parity(v)^c0 (verified R4).
__global__ __launch_bounds__(1024)
void pass_low(float* __restrict__ sre, float* __restrict__ sim,
              const float* __restrict__ param) {
    __shared__ __align__(16) char L[131072];
    const int tid = threadIdx.x, c = blockIdx.x;
    const int l = tid & 63, w = tid >> 6;
    G8 my = u3_lane(param, l < 23 ? l : 22);
    float4 xr[4], xi[4];

    float4* R4p = (float4*)sre;
    float4* I4p = (float4*)sim;
    const size_t cb = ((size_t)c) << 12;
    const int sw0 = (w << 8) | l;
#pragma unroll
    for (int j = 0; j < 4; ++j) {
        size_t fi = cb + (size_t)(sw0 | (j << 6));
        xr[j] = R4p[fi]; xi[j] = I4p[fi];
    }
    const int b1 = l & 1, b2 = (l >> 1) & 1;
    const int h16 = (l >> 4) & 1, h32 = (l >> 5) & 1;

    // Epoch A
    { G8 g = gread(my,20); gate_dpp1(xr, xi, g, b1, 0); }
    { G8 g = gread(my,19); gate_dpp2(xr, xi, g, b2, 0); }
    { G8 g = gread(my,16); gate_x16(xr, xi, g, h16, h16); }
    { G8 g = gread(my,15); gate_x32(xr, xi, g, h32, h32); }
    { G8 g = gread(my,14); reg_gate0(xr, xi, g); }
    { G8 g = gread(my,13); reg_gate1(xr, xi, g); }

    // RT write (linear slots)
#pragma unroll
    for (int j = 0; j < 4; ++j) {
        int a = (sw0 | (j << 6)) << 4;
        *(float4*)(L + a) = xr[j];
        *(float4*)(L + a + 65536) = xi[j];
    }
    __syncthreads();
    // RT read: s = g2 | g3<<1 | g4<<2 ... = l'2 | l'3<<1 | l'0<<2 | l'1<<3 | w'<<4 | j'<<8 | l'4<<10 | l'5<<11
    const int sbase = ((l >> 2) & 3) | ((l & 3) << 2) | ((w & 15) << 4) | (((l >> 4) & 3) << 10);
#pragma unroll
    for (int j = 0; j < 4; ++j) {
        int a = (sbase | (j << 8)) << 4;
        xr[j] = *(const float4*)(L + a);
        xi[j] = *(const float4*)(L + a + 65536);
    }

    // Epoch B
    { G8 g = gread(my,18); gate_dpp1(xr, xi, g, b1, 0); }
    { G8 g = gread(my,17); gate_dpp2(xr, xi, g, b2, 0); }
    { G8 g = gread(my,12); reg_gate0(xr, xi, g); }
    { G8 g = gread(my,11); reg_gate1(xr, xi, g); }
    { G8 g = gread(my,10); gate_x16(xr, xi, g, h16, h16); }
    { G8 g = gread(my, 9); gate_x32(xr, xi, g, h32, h32); }

    // Gray-gather store (verified R4 formulas); v = sbase | (j<<8)
    const int px0 = pxor12(sbase);
    const int codd = c & 1;
    const int A12 = codd ? 0xFFF : 0;
    constexpr int PM[4] = {0, 0x1FF, 0x3FF, 0x200};  // pxor12(j<<8)
#pragma unroll
    for (int j = 0; j < 4; ++j) {
        int pxj = px0 ^ PM[j];
        int of4 = pxj ^ A12;
        int b = (pxj ^ codd) & 1;
        float s0r = xr[j].x, s1r = xr[j].y, s2r = xr[j].w, s3r = xr[j].z;
        float s0i = xi[j].x, s1i = xi[j].y, s2i = xi[j].w, s3i = xi[j].z;
        float o0r = b ? s3r : s0r, o1r = b ? s2r : s1r, o2r = b ? s1r : s2r, o3r = b ? s0r : s3r;
        float o0i = b ? s3i : s0i, o1i = b ? s2i : s1i, o2i = b ? s1i : s2i, o3i = b ? s0i : s3i;
        size_t oo = cb | (size_t)of4;
        R4p[oo] = make_float4(o0r, o1r, o2r, o3r);
        I4p[oo] = make_float4(o0i, o1i, o2i, o3i);
    }
}

extern "C" void kernel_launch(void* const* d_in, const int* in_sizes, int n_in,
                              void* d_out, int out_size, void* d_ws, size_t ws_size,
                              hipStream_t stream) {
    (void)in_sizes; (void)n_in; (void)d_ws; (void)ws_size; (void)out_size;
    const float* in_re = (const float*)d_in[0];
    const float* in_im = (const float*)d_in[1];
    const float* param = (const float*)d_in[2];
    float* out_re = (float*)d_out;
    float* out_im = (float*)d_out + NTOT;

    pass_high<<<512, 1024, 0, stream>>>(in_re, in_im, param, out_re, out_im);
    pass_low <<<512, 1024, 0, stream>>>(out_re, out_im, param);
}